// Round 3
// baseline (11799.826 us; speedup 1.0000x reference)
//
#include <hip/hip_runtime.h>
#include <stdint.h>

// ---------- types / helpers ----------
typedef __attribute__((ext_vector_type(8))) short short8;   // 8 bf16 in 4 VGPRs
typedef __attribute__((ext_vector_type(4))) float f32x4;

__device__ __forceinline__ unsigned short f32_to_bf16(float f) {
    unsigned int u = __float_as_uint(f);
    unsigned int r = (u + 0x7FFF + ((u >> 16) & 1)) >> 16;   // RNE
    return (unsigned short)r;
}
__device__ __forceinline__ float bf16_to_f32(unsigned short s) {
    return __uint_as_float(((unsigned int)s) << 16);
}

// ---------- prep kernels ----------
__global__ void cvt_bf16_kernel(const float* __restrict__ in,
                                unsigned short* __restrict__ out, int n) {
    int i = (blockIdx.x * blockDim.x + threadIdx.x) * 4;
    if (i >= n) return;
    float4 v = *(const float4*)(in + i);
    ushort4 o;
    o.x = f32_to_bf16(v.x);
    o.y = f32_to_bf16(v.y);
    o.z = f32_to_bf16(v.z);
    o.w = f32_to_bf16(v.w);
    *(ushort4*)(out + i) = o;
}

__global__ void bias_add_kernel(const float* __restrict__ bi,
                                const float* __restrict__ bh,
                                float* __restrict__ bias) {
    int i = blockIdx.x * blockDim.x + threadIdx.x;  // 4096
    bias[i] = bi[i] + bh[i];
}

__global__ void zero_kernel(unsigned int* __restrict__ p, int n) {
    int i = blockIdx.x * blockDim.x + threadIdx.x;
    if (i < n) p[i] = 0u;
}

// h0 [b][j] fp32 -> hG0 in B-fragment order:
// dword D = ((kq)*32 + b)*4 + i2, holding bf16 h[j = kq*8 + i2*2], h[j+1] for batch b.
__global__ void hG_init_kernel(const float* __restrict__ h0,
                               unsigned int* __restrict__ hG) {
    int D = blockIdx.x * blockDim.x + threadIdx.x;  // 16384
    int i2 = D & 3, b = (D >> 2) & 31, kq = D >> 7;
    int j = kq * 8 + i2 * 2;
    unsigned int lo = f32_to_bf16(h0[b * 1024 + j]);
    unsigned int hi = f32_to_bf16(h0[b * 1024 + j + 1]);
    hG[D] = lo | (hi << 16);
}

// ---------- phase 1: xg[r][g] = bf16( x[r][:]·W_ih[g][:] + bias[g] ), r=b*512+t ----------
#define LDP 40  // padded LDS row pitch (shorts): 2-way conflicts only (free)

__global__ __launch_bounds__(256) void gemm_xproj(
    const unsigned short* __restrict__ A,   // x bf16 [16384][1024]
    const unsigned short* __restrict__ B,   // W_ih bf16 [4096][1024]
    const float* __restrict__ bias,         // [4096]
    unsigned short* __restrict__ C) {       // xg bf16 [16384][4096]
    __shared__ unsigned short As[64][LDP];
    __shared__ unsigned short Bs[64][LDP];
    const int tid  = threadIdx.x;
    const int lane = tid & 63;
    const int wave = tid >> 6;
    const int m0 = blockIdx.y * 64;
    const int n0 = blockIdx.x * 64;
    const int wm = (wave & 1) * 32;
    const int wn = (wave >> 1) * 32;

    f32x4 acc[2][2] = {};

    const int sr = tid >> 2;
    const int sk = (tid & 3) * 8;
    const int fr = lane & 15;
    const int fk = (lane >> 4) * 8;

    for (int k0 = 0; k0 < 1024; k0 += 32) {
        uint4 av = *(const uint4*)&A[(m0 + sr) * 1024 + k0 + sk];
        uint4 bv = *(const uint4*)&B[(n0 + sr) * 1024 + k0 + sk];
        __syncthreads();
        *(uint4*)&As[sr][sk] = av;
        *(uint4*)&Bs[sr][sk] = bv;
        __syncthreads();
        short8 a0 = *(const short8*)&As[wm + fr][fk];
        short8 a1 = *(const short8*)&As[wm + 16 + fr][fk];
        short8 b0 = *(const short8*)&Bs[wn + fr][fk];
        short8 b1 = *(const short8*)&Bs[wn + 16 + fr][fk];
        acc[0][0] = __builtin_amdgcn_mfma_f32_16x16x32_bf16(a0, b0, acc[0][0], 0, 0, 0);
        acc[0][1] = __builtin_amdgcn_mfma_f32_16x16x32_bf16(a0, b1, acc[0][1], 0, 0, 0);
        acc[1][0] = __builtin_amdgcn_mfma_f32_16x16x32_bf16(a1, b0, acc[1][0], 0, 0, 0);
        acc[1][1] = __builtin_amdgcn_mfma_f32_16x16x32_bf16(a1, b1, acc[1][1], 0, 0, 0);
    }

    const int col = lane & 15;
    const int rq  = (lane >> 4) * 4;
    for (int mt = 0; mt < 2; mt++) {
        for (int nt = 0; nt < 2; nt++) {
            int gcol = n0 + wn + nt * 16 + col;
            float bv = bias[gcol];
            for (int r = 0; r < 4; r++) {
                int grow = m0 + wm + mt * 16 + rq + r;
                C[(size_t)grow * 4096 + gcol] = f32_to_bf16(acc[mt][nt][r] + bv);
            }
        }
    }
}

// ---------- phase 2: persistent recurrence, all 512 steps in one launch ----------
// 256 blocks x 512 threads. Block bid owns hidden units j0=4*bid..+3 (16 gate rows).
// W_hh slice staged once in LDS as bf16 A-fragments (32 KB).
// Per step: C[m=gate16][n=batch32] via 16x16x32 MFMA, K=1024 split 4 ways x 2 n-tiles
// over 8 waves; LDS reduce; epilogue threads (tid<128) own (jj,b), keep c in VGPRs.
// h exchanged through LLC: sc1 (device-scope) stores/loads in B-fragment order.
// Barrier: per-step flag per block, release-store + acquire-poll (no RMW contention).
__global__ __launch_bounds__(512, 4) void lstm_persist(
    const float* __restrict__ Whh,          // [4096][1024] fp32
    const unsigned short* __restrict__ xg,  // bf16 [16384][4096], bias folded
    const float* __restrict__ c0,           // [32][1024] fp32
    unsigned int* __restrict__ hG0,         // 16384 dwords, frag-order h (t even reads)
    unsigned int* __restrict__ hG1,
    unsigned int* __restrict__ flags,       // [512][256]
    float* __restrict__ out) {              // [32][1024] fp32
    __shared__ unsigned short Afrag[16384];     // 32 KB
    __shared__ float partial[8][16][16];        // 8 KB  [wave][m][n_local]
    __shared__ unsigned short hout[128];        // [b*4 + jj]

    const int tid  = threadIdx.x;
    const int bid  = blockIdx.x;
    const int j0   = bid * 4;
    const int lane = tid & 63;
    const int wave = tid >> 6;
    const int ks   = wave >> 1;   // K-split 0..3 (256 k each)
    const int nt   = wave & 1;    // n-tile (batch 0-15 / 16-31)
    const int col  = lane & 15;
    const int quad = lane >> 4;

    // ---- stage W_hh slice -> A-fragment order (once) ----
    // chunk c: kq = c>>4 (k-octet, k = kq*8..+7), m = c&15 (m = q*4 + jj)
    for (int c = tid; c < 2048; c += 512) {
        int kq = c >> 4, m = c & 15;
        int q = m >> 2, jj = m & 3;
        const float* wr = Whh + (size_t)(q * 1024 + j0 + jj) * 1024 + kq * 8;
        float4 wa = *(const float4*)wr;
        float4 wb = *(const float4*)(wr + 4);
        short8 v;
        v[0] = f32_to_bf16(wa.x); v[1] = f32_to_bf16(wa.y);
        v[2] = f32_to_bf16(wa.z); v[3] = f32_to_bf16(wa.w);
        v[4] = f32_to_bf16(wb.x); v[5] = f32_to_bf16(wb.y);
        v[6] = f32_to_bf16(wb.z); v[7] = f32_to_bf16(wb.w);
        *(short8*)&Afrag[c * 8] = v;
    }

    const int ejj = (tid >> 5) & 3;  // epilogue ids (valid for tid<128)
    const int eb  = tid & 31;
    float cst = 0.f;
    if (tid < 128) cst = c0[eb * 1024 + j0 + ejj];
    __syncthreads();

    const int kq_j = j0 >> 3;          // this block's h-output k-octet
    const int i02  = (j0 & 7) >> 1;    // dword sub-offset 0 or 2

    for (int t = 0; t < 512; ++t) {
        const unsigned int* hR = (t & 1) ? hG1 : hG0;
        unsigned int*       hW = (t & 1) ? hG0 : hG1;

        // prefetch xg gate inputs (independent of h)
        float xz0 = 0.f, xz1 = 0.f, xz2 = 0.f, xz3 = 0.f;
        if (tid < 128) {
            const unsigned short* p = xg + (size_t)(eb * 512 + t) * 4096 + j0 + ejj;
            xz0 = bf16_to_f32(p[0]);
            xz1 = bf16_to_f32(p[1024]);
            xz2 = bf16_to_f32(p[2048]);
            xz3 = bf16_to_f32(p[3072]);
        }

        // B-fragments: device-coherent loads from LLC (bypass stale L1/L2)
        uint4 bv[8];
        const int brow = nt * 16 + col;
#pragma unroll
        for (int u = 0; u < 8; ++u) {
            int kc = ks * 8 + u;
            const unsigned int* p = hR + ((kc * 4 + quad) * 32 + brow) * 4;
            asm volatile("global_load_dwordx4 %0, %1, off sc1"
                         : "=v"(bv[u]) : "v"(p) : "memory");
        }
        asm volatile("s_waitcnt vmcnt(0)" ::: "memory");

        f32x4 acc = {0.f, 0.f, 0.f, 0.f};
#pragma unroll
        for (int u = 0; u < 8; ++u) {
            int kc = ks * 8 + u;
            short8 af = *(const short8*)&Afrag[((kc * 4 + quad) * 16 + col) * 8];
            union { uint4 u4; short8 s8; } cv;
            cv.u4 = bv[u];
            acc = __builtin_amdgcn_mfma_f32_16x16x32_bf16(af, cv.s8, acc, 0, 0, 0);
        }
#pragma unroll
        for (int r = 0; r < 4; ++r) partial[wave][quad * 4 + r][col] = acc[r];
        __syncthreads();

        if (tid < 128) {
            const int ntb = eb >> 4, nl = eb & 15;
            float z[4];
#pragma unroll
            for (int q = 0; q < 4; ++q) {
                int m = q * 4 + ejj;
                z[q] = partial[0 + ntb][m][nl] + partial[2 + ntb][m][nl] +
                       partial[4 + ntb][m][nl] + partial[6 + ntb][m][nl];
            }
            z[0] += xz0; z[1] += xz1; z[2] += xz2; z[3] += xz3;
            float ig = 1.f / (1.f + __expf(-z[0]));
            float fg = 1.f / (1.f + __expf(-z[1]));
            float gg = tanhf(z[2]);
            float og = 1.f / (1.f + __expf(-z[3]));
            cst = fg * cst + ig * gg;
            float hn = og * tanhf(cst);
            hout[eb * 4 + ejj] = f32_to_bf16(hn);
            if (t == 511) out[eb * 1024 + j0 + ejj] = hn;  // final output
        }
        if (t == 511) break;  // uniform; no h publish needed after last step
        __syncthreads();

        // publish this block's 4 h values per batch (device-coherent stores)
        if (tid < 32) {
            unsigned int d0 = (unsigned int)hout[tid * 4 + 0] |
                              ((unsigned int)hout[tid * 4 + 1] << 16);
            unsigned int d1 = (unsigned int)hout[tid * 4 + 2] |
                              ((unsigned int)hout[tid * 4 + 3] << 16);
            uint2 dw; dw.x = d0; dw.y = d1;
            unsigned int* p = hW + (kq_j * 32 + tid) * 4 + i02;
            asm volatile("global_store_dwordx2 %0, %1, off sc1\n\ts_waitcnt vmcnt(0)"
                         :: "v"(p), "v"(dw) : "memory");
        }
        __syncthreads();

        // barrier: arrive (release) then wait for all 256 blocks (acquire)
        if (tid == 0)
            __hip_atomic_store(&flags[t * 256 + bid], 1u,
                               __ATOMIC_RELEASE, __HIP_MEMORY_SCOPE_AGENT);
        if (tid < 256) {
            while (__hip_atomic_load(&flags[t * 256 + tid],
                                     __ATOMIC_ACQUIRE, __HIP_MEMORY_SCOPE_AGENT) == 0u)
                __builtin_amdgcn_s_sleep(1);
        }
        __syncthreads();
    }
}

// ---------- launch ----------
extern "C" void kernel_launch(void* const* d_in, const int* in_sizes, int n_in,
                              void* d_out, int out_size, void* d_ws, size_t ws_size,
                              hipStream_t stream) {
    const float* x    = (const float*)d_in[0];  // [32][512][1024]
    const float* h0   = (const float*)d_in[1];  // [32][1024]
    const float* c0   = (const float*)d_in[2];  // [32][1024]
    const float* Wih  = (const float*)d_in[3];  // [4096][1024]
    const float* Whh  = (const float*)d_in[4];  // [4096][1024]
    const float* b_ih = (const float*)d_in[5];  // [4096]
    const float* b_hh = (const float*)d_in[6];  // [4096]
    float* out = (float*)d_out;
    char* ws = (char*)d_ws;

    // workspace layout (fits in the round-2-proven 176,439,296 B):
    //   xg   @ 0          134217728 B (bf16, live through persistent phase)
    //   xA   @ 134217728   33554432 B (bf16 x; DEAD after gemm -> flags overlay)
    //   wB   @ 167772160    8388608 B (bf16 W_ih)
    //   bias @ 176160768      16384 B
    //   hG0  @ 176177152      65536 B
    //   hG1  @ 176242688      65536 B  (end 176308224)
    unsigned short* xg   = (unsigned short*)(ws);
    unsigned short* xA   = (unsigned short*)(ws + 134217728);
    unsigned short* wB   = (unsigned short*)(ws + 167772160);
    float*          bias = (float*)(ws + 176160768);
    unsigned int*   hG0  = (unsigned int*)(ws + 176177152);
    unsigned int*   hG1  = (unsigned int*)(ws + 176242688);
    unsigned int*   flags = (unsigned int*)(ws + 134217728);  // overlays xA after gemm

    cvt_bf16_kernel<<<16384, 256, 0, stream>>>(x, xA, 16777216);
    cvt_bf16_kernel<<<4096, 256, 0, stream>>>(Wih, wB, 4194304);
    bias_add_kernel<<<16, 256, 0, stream>>>(b_ih, b_hh, bias);

    dim3 g1(64, 256);
    gemm_xproj<<<g1, 256, 0, stream>>>(xA, wB, bias, xg);

    // xA dead from here; reuse as flag storage
    zero_kernel<<<512, 256, 0, stream>>>(flags, 512 * 256);
    hG_init_kernel<<<64, 256, 0, stream>>>(h0, hG0);

    lstm_persist<<<256, 512, 0, stream>>>(Whh, xg, c0, hG0, hG1, flags, out);
}

// Round 4
// 3742.013 us; speedup vs baseline: 3.1533x; 3.1533x over previous
//
#include <hip/hip_runtime.h>
#include <stdint.h>

// ---------- types / helpers ----------
typedef __attribute__((ext_vector_type(8))) short short8;   // 8 bf16 in 4 VGPRs
typedef __attribute__((ext_vector_type(4))) float f32x4;

__device__ __forceinline__ unsigned short f32_to_bf16(float f) {
    unsigned int u = __float_as_uint(f);
    unsigned int r = (u + 0x7FFF + ((u >> 16) & 1)) >> 16;   // RNE
    return (unsigned short)r;
}
__device__ __forceinline__ float bf16_to_f32(unsigned short s) {
    return __uint_as_float(((unsigned int)s) << 16);
}

// ---------- prep kernels ----------
__global__ void cvt_bf16_kernel(const float* __restrict__ in,
                                unsigned short* __restrict__ out, int n) {
    int i = (blockIdx.x * blockDim.x + threadIdx.x) * 4;
    if (i >= n) return;
    float4 v = *(const float4*)(in + i);
    ushort4 o;
    o.x = f32_to_bf16(v.x);
    o.y = f32_to_bf16(v.y);
    o.z = f32_to_bf16(v.z);
    o.w = f32_to_bf16(v.w);
    *(ushort4*)(out + i) = o;
}

__global__ void bias_add_kernel(const float* __restrict__ bi,
                                const float* __restrict__ bh,
                                float* __restrict__ bias) {
    int i = blockIdx.x * blockDim.x + threadIdx.x;  // 4096
    bias[i] = bi[i] + bh[i];
}

__global__ void zero_kernel(unsigned int* __restrict__ p, int n) {
    int i = blockIdx.x * blockDim.x + threadIdx.x;
    if (i < n) p[i] = 0u;
}

// h0 [b][j] fp32 -> hG0 in B-fragment order:
// dword D = ((kq)*32 + b)*4 + i2, holding bf16 h[j = kq*8 + i2*2], h[j+1] for batch b.
__global__ void hG_init_kernel(const float* __restrict__ h0,
                               unsigned int* __restrict__ hG) {
    int D = blockIdx.x * blockDim.x + threadIdx.x;  // 16384
    int i2 = D & 3, b = (D >> 2) & 31, kq = D >> 7;
    int j = kq * 8 + i2 * 2;
    unsigned int lo = f32_to_bf16(h0[b * 1024 + j]);
    unsigned int hi = f32_to_bf16(h0[b * 1024 + j + 1]);
    hG[D] = lo | (hi << 16);
}

// ---------- phase 1: xg[r][g] = bf16( x[r][:]·W_ih[g][:] + bias[g] ), r=b*512+t ----------
#define LDP 40  // padded LDS row pitch (shorts): 2-way conflicts only (free)

__global__ __launch_bounds__(256) void gemm_xproj(
    const unsigned short* __restrict__ A,   // x bf16 [16384][1024]
    const unsigned short* __restrict__ B,   // W_ih bf16 [4096][1024]
    const float* __restrict__ bias,         // [4096]
    unsigned short* __restrict__ C) {       // xg bf16 [16384][4096]
    __shared__ unsigned short As[64][LDP];
    __shared__ unsigned short Bs[64][LDP];
    const int tid  = threadIdx.x;
    const int lane = tid & 63;
    const int wave = tid >> 6;
    const int m0 = blockIdx.y * 64;
    const int n0 = blockIdx.x * 64;
    const int wm = (wave & 1) * 32;
    const int wn = (wave >> 1) * 32;

    f32x4 acc[2][2] = {};

    const int sr = tid >> 2;
    const int sk = (tid & 3) * 8;
    const int fr = lane & 15;
    const int fk = (lane >> 4) * 8;

    for (int k0 = 0; k0 < 1024; k0 += 32) {
        uint4 av = *(const uint4*)&A[(m0 + sr) * 1024 + k0 + sk];
        uint4 bv = *(const uint4*)&B[(n0 + sr) * 1024 + k0 + sk];
        __syncthreads();
        *(uint4*)&As[sr][sk] = av;
        *(uint4*)&Bs[sr][sk] = bv;
        __syncthreads();
        short8 a0 = *(const short8*)&As[wm + fr][fk];
        short8 a1 = *(const short8*)&As[wm + 16 + fr][fk];
        short8 b0 = *(const short8*)&Bs[wn + fr][fk];
        short8 b1 = *(const short8*)&Bs[wn + 16 + fr][fk];
        acc[0][0] = __builtin_amdgcn_mfma_f32_16x16x32_bf16(a0, b0, acc[0][0], 0, 0, 0);
        acc[0][1] = __builtin_amdgcn_mfma_f32_16x16x32_bf16(a0, b1, acc[0][1], 0, 0, 0);
        acc[1][0] = __builtin_amdgcn_mfma_f32_16x16x32_bf16(a1, b0, acc[1][0], 0, 0, 0);
        acc[1][1] = __builtin_amdgcn_mfma_f32_16x16x32_bf16(a1, b1, acc[1][1], 0, 0, 0);
    }

    const int col = lane & 15;
    const int rq  = (lane >> 4) * 4;
    for (int mt = 0; mt < 2; mt++) {
        for (int nt = 0; nt < 2; nt++) {
            int gcol = n0 + wn + nt * 16 + col;
            float bv = bias[gcol];
            for (int r = 0; r < 4; r++) {
                int grow = m0 + wm + mt * 16 + rq + r;
                C[(size_t)grow * 4096 + gcol] = f32_to_bf16(acc[mt][nt][r] + bv);
            }
        }
    }
}

// ---------- phase 2: persistent recurrence, all 512 steps in one launch ----------
// 256 blocks x 512 threads. Block bid owns hidden units j0=4*bid..+3 (16 gate rows).
// W_hh slice staged once in LDS as bf16 A-fragments (32 KB).
// Per step: C[m=gate16][n=batch32] via 16x16x32 MFMA, K=1024 split 4 ways x 2 n-tiles
// over 8 waves; LDS reduce; epilogue threads (tid<128) own (jj,b), keep c in VGPRs.
// ALL cross-block traffic (h, flags) via raw sc0/sc1 LLC-coherent loads/stores —
// NO compiler atomics (their buffer_wbl2/buffer_inv cache-maintenance storm was
// the round-3 22 us/step regression).
__global__ __launch_bounds__(512, 4) void lstm_persist(
    const float* __restrict__ Whh,          // [4096][1024] fp32
    const unsigned short* __restrict__ xg,  // bf16 [16384][4096], bias folded
    const float* __restrict__ c0,           // [32][1024] fp32
    unsigned int* __restrict__ hG0,         // 16384 dwords, frag-order h (t even reads)
    unsigned int* __restrict__ hG1,
    unsigned int* __restrict__ flags,       // [512][256]
    float* __restrict__ out) {              // [32][1024] fp32
    __shared__ unsigned short Afrag[16384];     // 32 KB
    __shared__ float partial[8][16][16];        // 8 KB  [wave][m][n_local]
    __shared__ unsigned short hout[128];        // [b*4 + jj]

    const int tid  = threadIdx.x;
    const int bid  = blockIdx.x;
    const int j0   = bid * 4;
    const int lane = tid & 63;
    const int wave = tid >> 6;
    const int ks   = wave >> 1;   // K-split 0..3 (256 k each)
    const int nt   = wave & 1;    // n-tile (batch 0-15 / 16-31)
    const int col  = lane & 15;
    const int quad = lane >> 4;

    // ---- stage W_hh slice -> A-fragment order (once) ----
    for (int c = tid; c < 2048; c += 512) {
        int kq = c >> 4, m = c & 15;
        int q = m >> 2, jj = m & 3;
        const float* wr = Whh + (size_t)(q * 1024 + j0 + jj) * 1024 + kq * 8;
        float4 wa = *(const float4*)wr;
        float4 wb = *(const float4*)(wr + 4);
        short8 v;
        v[0] = f32_to_bf16(wa.x); v[1] = f32_to_bf16(wa.y);
        v[2] = f32_to_bf16(wa.z); v[3] = f32_to_bf16(wa.w);
        v[4] = f32_to_bf16(wb.x); v[5] = f32_to_bf16(wb.y);
        v[6] = f32_to_bf16(wb.z); v[7] = f32_to_bf16(wb.w);
        *(short8*)&Afrag[c * 8] = v;
    }

    const int ejj = (tid >> 5) & 3;  // epilogue ids (valid for tid<128)
    const int eb  = tid & 31;
    float cst = 0.f;
    if (tid < 128) cst = c0[eb * 1024 + j0 + ejj];
    __syncthreads();

    const int kq_j = j0 >> 3;          // this block's h-output k-octet
    const int i02  = (j0 & 7) >> 1;    // dword sub-offset 0 or 2

    for (int t = 0; t < 512; ++t) {
        const unsigned int* hR = (t & 1) ? hG1 : hG0;
        unsigned int*       hW = (t & 1) ? hG0 : hG1;

        // prefetch xg gate inputs (independent of h)
        float xz0 = 0.f, xz1 = 0.f, xz2 = 0.f, xz3 = 0.f;
        if (tid < 128) {
            const unsigned short* p = xg + (size_t)(eb * 512 + t) * 4096 + j0 + ejj;
            xz0 = bf16_to_f32(p[0]);
            xz1 = bf16_to_f32(p[1024]);
            xz2 = bf16_to_f32(p[2048]);
            xz3 = bf16_to_f32(p[3072]);
        }

        // B-fragments: LLC-coherent loads (h(t) published before prev barrier)
        uint4 bv[8];
        const int brow = nt * 16 + col;
#pragma unroll
        for (int u = 0; u < 8; ++u) {
            int kc = ks * 8 + u;
            const unsigned int* p = hR + ((kc * 4 + quad) * 32 + brow) * 4;
            asm volatile("global_load_dwordx4 %0, %1, off sc1"
                         : "=v"(bv[u]) : "v"(p) : "memory");
        }
        asm volatile("s_waitcnt vmcnt(0)" ::: "memory");

        f32x4 acc = {0.f, 0.f, 0.f, 0.f};
#pragma unroll
        for (int u = 0; u < 8; ++u) {
            int kc = ks * 8 + u;
            short8 af = *(const short8*)&Afrag[((kc * 4 + quad) * 16 + col) * 8];
            union { uint4 u4; short8 s8; } cv;
            cv.u4 = bv[u];
            acc = __builtin_amdgcn_mfma_f32_16x16x32_bf16(af, cv.s8, acc, 0, 0, 0);
        }
#pragma unroll
        for (int r = 0; r < 4; ++r) partial[wave][quad * 4 + r][col] = acc[r];
        __syncthreads();

        if (tid < 128) {
            const int ntb = eb >> 4, nl = eb & 15;
            float z[4];
#pragma unroll
            for (int q = 0; q < 4; ++q) {
                int m = q * 4 + ejj;
                z[q] = partial[0 + ntb][m][nl] + partial[2 + ntb][m][nl] +
                       partial[4 + ntb][m][nl] + partial[6 + ntb][m][nl];
            }
            z[0] += xz0; z[1] += xz1; z[2] += xz2; z[3] += xz3;
            float ig = 1.f / (1.f + __expf(-z[0]));
            float fg = 1.f / (1.f + __expf(-z[1]));
            float gg = tanhf(z[2]);
            float og = 1.f / (1.f + __expf(-z[3]));
            cst = fg * cst + ig * gg;
            float hn = og * tanhf(cst);
            hout[eb * 4 + ejj] = f32_to_bf16(hn);
            if (t == 511) out[eb * 1024 + j0 + ejj] = hn;  // final output
        }
        if (t == 511) break;  // uniform; no h publish needed after last step
        __syncthreads();

        // publish this block's 4 h values per batch (LLC write-through),
        // drain vmcnt BEFORE the flag store issues -> h visible before flag.
        if (tid < 32) {
            unsigned int d0 = (unsigned int)hout[tid * 4 + 0] |
                              ((unsigned int)hout[tid * 4 + 1] << 16);
            unsigned int d1 = (unsigned int)hout[tid * 4 + 2] |
                              ((unsigned int)hout[tid * 4 + 3] << 16);
            uint2 dw; dw.x = d0; dw.y = d1;
            unsigned int* p = hW + (kq_j * 32 + tid) * 4 + i02;
            asm volatile("global_store_dwordx2 %0, %1, off sc1\n\ts_waitcnt vmcnt(0)"
                         :: "v"(p), "v"(dw) : "memory");
        }
        __syncthreads();

        // barrier arrive: plain LLC store of 1 (no cache-maintenance ops)
        if (tid == 0) {
            unsigned int one = 1u;
            asm volatile("global_store_dword %0, %1, off sc0 sc1"
                         :: "v"(flags + t * 256 + bid), "v"(one) : "memory");
        }
        // barrier wait: relaxed LLC poll, one flag per thread
        if (tid < 256) {
            const unsigned int* fp = flags + t * 256 + tid;
            unsigned int v;
            while (true) {
                asm volatile("global_load_dword %0, %1, off sc0 sc1\n\ts_waitcnt vmcnt(0)"
                             : "=v"(v) : "v"(fp) : "memory");
                if (v != 0u) break;
                __builtin_amdgcn_s_sleep(1);
            }
        }
        __syncthreads();
    }
}

// ---------- launch ----------
extern "C" void kernel_launch(void* const* d_in, const int* in_sizes, int n_in,
                              void* d_out, int out_size, void* d_ws, size_t ws_size,
                              hipStream_t stream) {
    const float* x    = (const float*)d_in[0];  // [32][512][1024]
    const float* h0   = (const float*)d_in[1];  // [32][1024]
    const float* c0   = (const float*)d_in[2];  // [32][1024]
    const float* Wih  = (const float*)d_in[3];  // [4096][1024]
    const float* Whh  = (const float*)d_in[4];  // [4096][1024]
    const float* b_ih = (const float*)d_in[5];  // [4096]
    const float* b_hh = (const float*)d_in[6];  // [4096]
    float* out = (float*)d_out;
    char* ws = (char*)d_ws;

    // workspace layout (fits in the round-2-proven 176,439,296 B):
    //   xg    @ 0          134217728 B (bf16, live through persistent phase)
    //   xA    @ 134217728   33554432 B (bf16 x; DEAD after gemm -> flags overlay)
    //   wB    @ 167772160    8388608 B (bf16 W_ih)
    //   bias  @ 176160768      16384 B
    //   hG0   @ 176177152      65536 B
    //   hG1   @ 176242688      65536 B  (end 176308224)
    unsigned short* xg   = (unsigned short*)(ws);
    unsigned short* xA   = (unsigned short*)(ws + 134217728);
    unsigned short* wB   = (unsigned short*)(ws + 167772160);
    float*          bias = (float*)(ws + 176160768);
    unsigned int*   hG0  = (unsigned int*)(ws + 176177152);
    unsigned int*   hG1  = (unsigned int*)(ws + 176242688);
    unsigned int*   flags = (unsigned int*)(ws + 134217728);  // overlays xA after gemm

    cvt_bf16_kernel<<<16384, 256, 0, stream>>>(x, xA, 16777216);
    cvt_bf16_kernel<<<4096, 256, 0, stream>>>(Wih, wB, 4194304);
    bias_add_kernel<<<16, 256, 0, stream>>>(b_ih, b_hh, bias);

    dim3 g1(64, 256);
    gemm_xproj<<<g1, 256, 0, stream>>>(xA, wB, bias, xg);

    // xA dead from here; reuse as flag storage
    zero_kernel<<<512, 256, 0, stream>>>(flags, 512 * 256);
    hG_init_kernel<<<64, 256, 0, stream>>>(h0, hG0);

    lstm_persist<<<256, 512, 0, stream>>>(Whh, xg, c0, hG0, hG1, flags, out);
}